// Round 1
// baseline (266.816 us; speedup 1.0000x reference)
//
#include <hip/hip_runtime.h>
#include <hip/hip_bf16.h>

#define ENC 2048
#define ADIM 512
#define DEC 512
#define NBATCH 128
#define NL 196
#define MTOT (NBATCH * NL)   // 25088

typedef __attribute__((ext_vector_type(8))) short short8;
typedef __attribute__((ext_vector_type(4))) float f32x4;
typedef __attribute__((ext_vector_type(4))) unsigned int u32x4;

__device__ __forceinline__ unsigned short f2bf(float f) {
    __hip_bfloat16 h = __float2bfloat16(f);
    union { __hip_bfloat16 h; unsigned short u; } cv; cv.h = h; return cv.u;
}
__device__ __forceinline__ unsigned int f2bf2(float lo, float hi) {
    __hip_bfloat162 h = __float22bfloat162_rn(float2{lo, hi});
    union { __hip_bfloat162 h; unsigned int u; } cv; cv.h = h; return cv.u;
}

// ---------------- kernel 1: w_ah = hidden @ W_w + W_b  [128 x 512] ----------------
__global__ void wah_kernel(const float* __restrict__ hidden, const float* __restrict__ Ww,
                           const float* __restrict__ Wb, float* __restrict__ wah) {
    __shared__ float hs[DEC];
    const int b = blockIdx.x, a = threadIdx.x;   // block 512 threads
    hs[a] = hidden[b * DEC + a];
    __syncthreads();
    float acc = Wb[a];
    #pragma unroll 8
    for (int d = 0; d < DEC; ++d)
        acc += hs[d] * Ww[d * ADIM + a];
    wah[b * ADIM + a] = acc;
}

// ---------------- kernel 2: U_w [K=2048][N=512] fp32 -> uwT [N][K] bf16 ----------------
__global__ void transpose_uw(const float* __restrict__ Uw, unsigned short* __restrict__ uwT) {
    __shared__ float t[32][33];
    const int k0 = blockIdx.x * 32, n0 = blockIdx.y * 32;
    const int tx = threadIdx.x, ty = threadIdx.y;   // 32 x 8
    #pragma unroll
    for (int i = 0; i < 4; ++i)
        t[ty + 8 * i][tx] = Uw[(size_t)(k0 + ty + 8 * i) * ADIM + n0 + tx];
    __syncthreads();
    #pragma unroll
    for (int i = 0; i < 4; ++i)
        uwT[(size_t)(n0 + ty + 8 * i) * ENC + k0 + tx] = f2bf(t[tx][ty + 8 * i]);
}

// ---------------- kernel 3: fused GEMM + tanh + A_w-dot -> score partials ----------------
// C tile 128x128, BK=64, 4 waves (2x2), wave tile 64x64, mfma_f32_16x16x32_bf16
__global__ __launch_bounds__(256, 2) void gemm_score_kernel(
    const float* __restrict__ feat, const unsigned short* __restrict__ uwT,
    const float* __restrict__ Ub, const float* __restrict__ wahb,
    const float* __restrict__ Aw, float* __restrict__ part)
{
    __shared__ __align__(16) unsigned char AsB[32768];  // 2 x [128 rows][64 k] bf16, XOR-swizzled
    __shared__ __align__(16) unsigned char BsB[32768];  // 2 x [128 n  ][64 k] bf16, XOR-swizzled

    const int tid  = threadIdx.x;
    const int lane = tid & 63;
    const int w    = tid >> 6;
    const int wr   = w >> 1, wc = w & 1;
    const int l15  = lane & 15, ldr = lane >> 4;

    // bijective XCD swizzle: 784 blocks = 8 XCD chunks of 98
    const int bid  = blockIdx.x;
    const int work = (bid & 7) * 98 + (bid >> 3);
    const int mb   = work >> 2;    // 0..195
    const int nbk  = work & 3;     // 0..3

    // staging: thread -> (row = tid>>1, 32-elem half = (tid&1)*32)
    const int arow = tid >> 1;
    const int acol = (tid & 1) * 32;
    const float*          aptr = feat + (size_t)(mb * 128 + arow) * ENC + acol;
    const unsigned short* bptr = uwT  + (size_t)(nbk * 128 + arow) * ENC + acol;
    int wb[4];
    #pragma unroll
    for (int j = 0; j < 4; ++j)
        wb[j] = arow * 128 + ((acol * 2 + j * 16) ^ ((arow & 7) << 4));

    // fragment read byte offsets (same XOR swizzle)
    int abyte[4][2], bbyte[4][2];
    #pragma unroll
    for (int f = 0; f < 4; ++f) {
        const int r = wr * 64 + f * 16 + l15;
        const int n = wc * 64 + f * 16 + l15;
        #pragma unroll
        for (int ks = 0; ks < 2; ++ks) {
            const int kb = ks * 64 + ldr * 16;
            abyte[f][ks] = r * 128 + (kb ^ ((r & 7) << 4));
            bbyte[f][ks] = n * 128 + (kb ^ ((n & 7) << 4));
        }
    }

    f32x4 acc[4][4];
    #pragma unroll
    for (int i = 0; i < 4; ++i)
        #pragma unroll
        for (int j = 0; j < 4; ++j)
            acc[i][j] = (f32x4){0.f, 0.f, 0.f, 0.f};

    f32x4 ar[8];
    u32x4 br[4];

#define LOADS(KT) {                                                                   \
    _Pragma("unroll")                                                                 \
    for (int j = 0; j < 8; ++j) ar[j] = *(const f32x4*)(aptr + (size_t)(KT) * 64 + j * 4); \
    _Pragma("unroll")                                                                 \
    for (int j = 0; j < 4; ++j) br[j] = *(const u32x4*)(bptr + (size_t)(KT) * 64 + j * 8); \
}
#define WRITES(BUF) {                                                                 \
    _Pragma("unroll")                                                                 \
    for (int j = 0; j < 4; ++j) {                                                     \
        u32x4 wv;                                                                     \
        wv.x = f2bf2(ar[2*j].x,   ar[2*j].y);                                         \
        wv.y = f2bf2(ar[2*j].z,   ar[2*j].w);                                         \
        wv.z = f2bf2(ar[2*j+1].x, ar[2*j+1].y);                                       \
        wv.w = f2bf2(ar[2*j+1].z, ar[2*j+1].w);                                       \
        *(u32x4*)(AsB + (BUF) * 16384 + wb[j]) = wv;                                  \
        *(u32x4*)(BsB + (BUF) * 16384 + wb[j]) = br[j];                               \
    }                                                                                 \
}
#define COMPUTE(BUF) {                                                                \
    _Pragma("unroll")                                                                 \
    for (int ks = 0; ks < 2; ++ks) {                                                  \
        short8 af[4], bf[4];                                                          \
        _Pragma("unroll")                                                             \
        for (int f = 0; f < 4; ++f) {                                                 \
            af[f] = *(const short8*)(AsB + (BUF) * 16384 + abyte[f][ks]);             \
            bf[f] = *(const short8*)(BsB + (BUF) * 16384 + bbyte[f][ks]);             \
        }                                                                             \
        _Pragma("unroll")                                                             \
        for (int fm = 0; fm < 4; ++fm)                                                \
            _Pragma("unroll")                                                         \
            for (int fn = 0; fn < 4; ++fn)                                            \
                acc[fm][fn] = __builtin_amdgcn_mfma_f32_16x16x32_bf16(                \
                    af[fm], bf[fn], acc[fm][fn], 0, 0, 0);                            \
    }                                                                                 \
}

    LOADS(0); WRITES(0);
    __syncthreads();
    int cur = 0;
    for (int kt = 0; kt < 32; ++kt) {
        if (kt < 31) LOADS(kt + 1);     // issue globals early: latency hides under MFMA
        COMPUTE(cur);
        if (kt < 31) WRITES(cur ^ 1);   // cvt + ds_write into other buffer
        __syncthreads();
        cur ^= 1;
    }
#undef LOADS
#undef WRITES
#undef COMPUTE

    // epilogue: score partial = sum_c Aw[c] * tanh(acc + Ub[c] + wah[b][c]) over this block's 128 cols
    float ub4[4], aw4[4]; int cidx[4];
    #pragma unroll
    for (int f = 0; f < 4; ++f) {
        const int c = nbk * 128 + wc * 64 + f * 16 + l15;
        cidx[f] = c; ub4[f] = Ub[c]; aw4[f] = Aw[c];
    }
    #pragma unroll
    for (int fm = 0; fm < 4; ++fm) {
        #pragma unroll
        for (int r = 0; r < 4; ++r) {
            const int m = mb * 128 + wr * 64 + fm * 16 + ldr * 4 + r;
            const int b = m / NL;
            const float* wrow = wahb + b * ADIM;
            float s = 0.f;
            #pragma unroll
            for (int f = 0; f < 4; ++f)
                s += aw4[f] * tanhf(acc[fm][f][r] + ub4[f] + wrow[cidx[f]]);
            s += __shfl_xor(s, 1);
            s += __shfl_xor(s, 2);
            s += __shfl_xor(s, 4);
            s += __shfl_xor(s, 8);
            if (l15 == 0) part[(nbk * 2 + wc) * MTOT + m] = s;
        }
    }
}

// ---------------- kernel 4: reduce partials + softmax over L -> alpha ----------------
__global__ void softmax_kernel(const float* __restrict__ part, const float* __restrict__ Ab,
                               float* __restrict__ alpha) {
    const int b = blockIdx.x, t = threadIdx.x;   // 256 threads
    float sv = 0.f;
    if (t < NL) {
        sv = Ab[0];
        #pragma unroll
        for (int p = 0; p < 8; ++p) sv += part[p * MTOT + b * NL + t];
    }
    float v = (t < NL) ? sv : -3.4e38f;
    #pragma unroll
    for (int o = 32; o >= 1; o >>= 1) v = fmaxf(v, __shfl_xor(v, o));
    __shared__ float rm[4], rs[4];
    if ((t & 63) == 0) rm[t >> 6] = v;
    __syncthreads();
    const float bm = fmaxf(fmaxf(rm[0], rm[1]), fmaxf(rm[2], rm[3]));
    const float e = (t < NL) ? expf(sv - bm) : 0.f;
    float s = e;
    #pragma unroll
    for (int o = 32; o >= 1; o >>= 1) s += __shfl_xor(s, o);
    if ((t & 63) == 0) rs[t >> 6] = s;
    __syncthreads();
    const float bs = rs[0] + rs[1] + rs[2] + rs[3];
    if (t < NL) alpha[b * NL + t] = e / bs;
}

// ---------------- kernel 5: context[b][e] = sum_l alpha[b][l] * feat[b][l][e] ----------------
__global__ void context_kernel(const float* __restrict__ feat, const float* __restrict__ alpha,
                               float* __restrict__ ctx) {
    __shared__ float al[NL];
    const int b = blockIdx.x, chunk = blockIdx.y, t = threadIdx.x;  // 128 threads
    for (int i = t; i < NL; i += 128) al[i] = alpha[b * NL + i];
    __syncthreads();
    const int e0 = chunk * 512 + t * 4;
    const float* fp = feat + (size_t)b * NL * ENC + e0;
    f32x4 acc0 = (f32x4){0.f, 0.f, 0.f, 0.f};
    f32x4 acc1 = (f32x4){0.f, 0.f, 0.f, 0.f};
    #pragma unroll 2
    for (int l = 0; l < NL; l += 2) {
        f32x4 f0 = *(const f32x4*)(fp + (size_t)l * ENC);
        f32x4 f1 = *(const f32x4*)(fp + (size_t)(l + 1) * ENC);
        acc0 += al[l] * f0;
        acc1 += al[l + 1] * f1;
    }
    f32x4 rsum = acc0 + acc1;
    *(f32x4*)(ctx + (size_t)b * ENC + e0) = rsum;
}

extern "C" void kernel_launch(void* const* d_in, const int* in_sizes, int n_in,
                              void* d_out, int out_size, void* d_ws, size_t ws_size,
                              hipStream_t stream) {
    const float* feat   = (const float*)d_in[0];
    const float* hidden = (const float*)d_in[1];
    const float* Uw     = (const float*)d_in[2];
    const float* Ub     = (const float*)d_in[3];
    const float* Ww     = (const float*)d_in[4];
    const float* Wb     = (const float*)d_in[5];
    const float* Aw     = (const float*)d_in[6];
    const float* Ab     = (const float*)d_in[7];

    float* out   = (float*)d_out;
    float* alpha = out;              // [128*196]
    float* ctx   = out + MTOT;       // [128*2048]

    char* ws = (char*)d_ws;
    float*          wahb = (float*)ws;                                   // 256 KB
    unsigned short* uwT  = (unsigned short*)(ws + 262144);               // 2 MB
    float*          partb= (float*)(ws + 262144 + 2097152);              // 8*25088*4 = 784 KB

    wah_kernel<<<dim3(128), dim3(512), 0, stream>>>(hidden, Ww, Wb, wahb);
    transpose_uw<<<dim3(64, 16), dim3(32, 8), 0, stream>>>(Uw, uwT);
    gemm_score_kernel<<<dim3(784), dim3(256), 0, stream>>>(feat, uwT, Ub, wahb, Aw, partb);
    softmax_kernel<<<dim3(128), dim3(256), 0, stream>>>(partb, Ab, alpha);
    context_kernel<<<dim3(128, 4), dim3(128), 0, stream>>>(feat, alpha, ctx);
}

// Round 2
// 186.034 us; speedup vs baseline: 1.4342x; 1.4342x over previous
//
#include <hip/hip_runtime.h>
#include <hip/hip_bf16.h>

#define ENC 2048
#define ADIM 512
#define DEC 512
#define NBATCH 128
#define NL 196
#define MTOT (NBATCH * NL)   // 25088

typedef __attribute__((ext_vector_type(8))) short short8;
typedef __attribute__((ext_vector_type(4))) float f32x4;

__device__ __forceinline__ unsigned short f2bf(float f) {
    __hip_bfloat16 h = __float2bfloat16(f);
    union { __hip_bfloat16 h; unsigned short u; } cv; cv.h = h; return cv.u;
}
__device__ __forceinline__ unsigned int f2bf2(float lo, float hi) {
    __hip_bfloat162 h = __float22bfloat162_rn(float2{lo, hi});
    union { __hip_bfloat162 h; unsigned int u; } cv; cv.h = h; return cv.u;
}

// async global -> LDS, 16B per lane. lds pointer must be wave-uniform.
__device__ __forceinline__ void load_lds16(const void* g, void* l) {
    __builtin_amdgcn_global_load_lds(
        (const __attribute__((address_space(1))) unsigned int*)g,
        (__attribute__((address_space(3))) unsigned int*)l, 16, 0, 0);
}

// ---------------- kernel 1: w_ah = hidden @ W_w + W_b  [128 x 512] ----------------
__global__ void wah_kernel(const float* __restrict__ hidden, const float* __restrict__ Ww,
                           const float* __restrict__ Wb, float* __restrict__ wah) {
    __shared__ __align__(16) float hs[DEC];
    const int b = blockIdx.x, a = threadIdx.x;   // block 512 threads
    hs[a] = hidden[b * DEC + a];
    __syncthreads();
    float acc = Wb[a];
    #pragma unroll 4
    for (int d = 0; d < DEC; d += 4) {
        f32x4 h = *(const f32x4*)&hs[d];
        acc += h.x * Ww[(d    ) * ADIM + a];
        acc += h.y * Ww[(d + 1) * ADIM + a];
        acc += h.z * Ww[(d + 2) * ADIM + a];
        acc += h.w * Ww[(d + 3) * ADIM + a];
    }
    wah[b * ADIM + a] = acc;
}

// ---------------- kernel 2: U_w [K=2048][N=512] fp32 -> uwT [N][K] bf16 ----------------
__global__ void transpose_uw(const float* __restrict__ Uw, unsigned short* __restrict__ uwT) {
    __shared__ float t[32][33];
    const int k0 = blockIdx.x * 32, n0 = blockIdx.y * 32;
    const int tx = threadIdx.x, ty = threadIdx.y;   // 32 x 8
    #pragma unroll
    for (int i = 0; i < 4; ++i)
        t[ty + 8 * i][tx] = Uw[(size_t)(k0 + ty + 8 * i) * ADIM + n0 + tx];
    __syncthreads();
    #pragma unroll
    for (int i = 0; i < 4; ++i)
        uwT[(size_t)(n0 + ty + 8 * i) * ENC + k0 + tx] = f2bf(t[tx][ty + 8 * i]);
}

// ---------------- kernel 3: fused GEMM + tanh + A_w-dot -> score partials ----------------
// m97 structure: global_load_lds staging, single-buffer LDS, 2 barriers/K-step.
// C tile 128x128, BK=64, 4 waves (2x2), wave tile 64x64, mfma_f32_16x16x32_bf16.
// A staged as fp32 (swizzle s(r) = ((r&3)<<5)|((r&4)<<2) within 256B rows),
// B staged as bf16 (swizzle t(n) = (n&7)<<4 within 128B rows).
// Both swizzles applied on the GLOBAL SOURCE address (LDS dest linear) and on reads.
__global__ __launch_bounds__(256, 3) void gemm_score_kernel(
    const float* __restrict__ feat, const unsigned short* __restrict__ uwT,
    const float* __restrict__ Ub, const float* __restrict__ wahb,
    const float* __restrict__ Aw, float* __restrict__ part)
{
    __shared__ __align__(16) unsigned char As[32768];  // [128 r][64 k] fp32, swizzled
    __shared__ __align__(16) unsigned char Bs[16384];  // [128 n][64 k] bf16, swizzled

    const int tid  = threadIdx.x;
    const int lane = tid & 63;
    const int w    = tid >> 6;
    const int wr   = w >> 1, wc = w & 1;
    const int l15  = lane & 15, ldr = lane >> 4;

    // bijective XCD swizzle: 784 blocks = 8 XCD chunks of 98 (mb-major -> 4 nbk share A-panel in L2)
    const int bid  = blockIdx.x;
    const int work = (bid & 7) * 98 + (bid >> 3);
    const int mb   = work >> 2;    // 0..195
    const int nbk  = work & 3;     // 0..3

    // ---- DMA source pointers (pre-swizzled global addresses) ----
    const char* featb = (const char*)feat;
    const char* uwTb  = (const char*)uwT;
    const char* aSrc[8];
    #pragma unroll
    for (int c = 0; c < 8; ++c) {
        const int row   = w * 32 + c * 4 + ldr;                      // LDS row this lane fills
        const int inner = (l15 * 16) ^ (ldr << 5) ^ ((c & 1) << 4);  // (l15*16) ^ s(row)
        aSrc[c] = featb + (size_t)(mb * 128 + row) * (ENC * 4) + inner;
    }
    const char* bSrc[4];
    #pragma unroll
    for (int c = 0; c < 4; ++c) {
        const int n     = w * 32 + c * 8 + (lane >> 3);
        const int inner = ((lane & 7) * 16) ^ (((lane >> 3) & 7) << 4);  // ^ t(n)
        bSrc[c] = uwTb + (size_t)(nbk * 128 + n) * (ENC * 2) + inner;
    }
    unsigned char* aDst = As + w * 8192;   // + c*1024, wave-uniform
    unsigned char* bDst = Bs + w * 4096;

    // ---- fragment read byte offsets (same swizzles) ----
    const int sA = ((l15 & 3) << 5) | ((l15 & 4) << 2);
    int abyte[4][2][2], bbyte[4][2];
    #pragma unroll
    for (int f = 0; f < 4; ++f) {
        const int r = wr * 64 + f * 16 + l15;
        const int n = wc * 64 + f * 16 + l15;
        #pragma unroll
        for (int ks = 0; ks < 2; ++ks) {
            const int k4 = ks * 128 + ldr * 32;             // fp32 byte offset of k-group
            abyte[f][ks][0] = r * 256 + ((k4     ) ^ sA);
            abyte[f][ks][1] = r * 256 + ((k4 + 16) ^ sA);
            bbyte[f][ks]    = n * 128 + ((ks * 64 + ldr * 16) ^ ((n & 7) << 4));
        }
    }

    f32x4 acc[4][4];
    #pragma unroll
    for (int i = 0; i < 4; ++i)
        #pragma unroll
        for (int j = 0; j < 4; ++j)
            acc[i][j] = (f32x4){0.f, 0.f, 0.f, 0.f};

    #pragma unroll 1
    for (int kt = 0; kt < 32; ++kt) {
        __syncthreads();                      // prior compute done reading LDS
        #pragma unroll
        for (int c = 0; c < 8; ++c)
            load_lds16(aSrc[c] + (size_t)kt * 256, aDst + c * 1024);
        #pragma unroll
        for (int c = 0; c < 4; ++c)
            load_lds16(bSrc[c] + (size_t)kt * 128, bDst + c * 1024);
        __syncthreads();                      // compiler drains vmcnt before barrier -> tile ready

        #pragma unroll
        for (int ks = 0; ks < 2; ++ks) {
            short8 af[4], bf[4];
            #pragma unroll
            for (int f = 0; f < 4; ++f) {
                f32x4 lo = *(const f32x4*)(As + abyte[f][ks][0]);
                f32x4 hi = *(const f32x4*)(As + abyte[f][ks][1]);
                union { unsigned int u[4]; short8 s; } cv;
                cv.u[0] = f2bf2(lo.x, lo.y);
                cv.u[1] = f2bf2(lo.z, lo.w);
                cv.u[2] = f2bf2(hi.x, hi.y);
                cv.u[3] = f2bf2(hi.z, hi.w);
                af[f] = cv.s;
                bf[f] = *(const short8*)(Bs + bbyte[f][ks]);
            }
            #pragma unroll
            for (int fm = 0; fm < 4; ++fm)
                #pragma unroll
                for (int fn = 0; fn < 4; ++fn)
                    acc[fm][fn] = __builtin_amdgcn_mfma_f32_16x16x32_bf16(
                        af[fm], bf[fn], acc[fm][fn], 0, 0, 0);
        }
    }

    // epilogue: score partial = sum_c Aw[c] * tanh(acc + Ub[c] + wah[b][c]) over this block's 128 cols
    float ub4[4], aw4[4]; int cidx[4];
    #pragma unroll
    for (int f = 0; f < 4; ++f) {
        const int c = nbk * 128 + wc * 64 + f * 16 + l15;
        cidx[f] = c; ub4[f] = Ub[c]; aw4[f] = Aw[c];
    }
    #pragma unroll
    for (int fm = 0; fm < 4; ++fm) {
        #pragma unroll
        for (int r = 0; r < 4; ++r) {
            const int m = mb * 128 + wr * 64 + fm * 16 + ldr * 4 + r;
            const int b = m / NL;
            const float* wrow = wahb + b * ADIM;
            float s = 0.f;
            #pragma unroll
            for (int f = 0; f < 4; ++f)
                s += aw4[f] * tanhf(acc[fm][f][r] + ub4[f] + wrow[cidx[f]]);
            s += __shfl_xor(s, 1);
            s += __shfl_xor(s, 2);
            s += __shfl_xor(s, 4);
            s += __shfl_xor(s, 8);
            if (l15 == 0) part[(nbk * 2 + wc) * MTOT + m] = s;
        }
    }
}

// ---------------- kernel 4: reduce partials + softmax over L -> alpha ----------------
__global__ void softmax_kernel(const float* __restrict__ part, const float* __restrict__ Ab,
                               float* __restrict__ alpha) {
    const int b = blockIdx.x, t = threadIdx.x;   // 256 threads
    float sv = 0.f;
    if (t < NL) {
        sv = Ab[0];
        #pragma unroll
        for (int p = 0; p < 8; ++p) sv += part[p * MTOT + b * NL + t];
    }
    float v = (t < NL) ? sv : -3.4e38f;
    #pragma unroll
    for (int o = 32; o >= 1; o >>= 1) v = fmaxf(v, __shfl_xor(v, o));
    __shared__ float rm[4], rs[4];
    if ((t & 63) == 0) rm[t >> 6] = v;
    __syncthreads();
    const float bm = fmaxf(fmaxf(rm[0], rm[1]), fmaxf(rm[2], rm[3]));
    const float e = (t < NL) ? expf(sv - bm) : 0.f;
    float s = e;
    #pragma unroll
    for (int o = 32; o >= 1; o >>= 1) s += __shfl_xor(s, o);
    if ((t & 63) == 0) rs[t >> 6] = s;
    __syncthreads();
    const float bs = rs[0] + rs[1] + rs[2] + rs[3];
    if (t < NL) alpha[b * NL + t] = e / bs;
}

// ---------------- kernel 5: context[b][e] = sum_l alpha[b][l] * feat[b][l][e] ----------------
__global__ void context_kernel(const float* __restrict__ feat, const float* __restrict__ alpha,
                               float* __restrict__ ctx) {
    __shared__ float al[NL];
    const int b = blockIdx.x, chunk = blockIdx.y, t = threadIdx.x;  // 128 threads
    for (int i = t; i < NL; i += 128) al[i] = alpha[b * NL + i];
    __syncthreads();
    const int e0 = chunk * 512 + t * 4;
    const float* fp = feat + (size_t)b * NL * ENC + e0;
    f32x4 acc0 = (f32x4){0.f, 0.f, 0.f, 0.f};
    f32x4 acc1 = (f32x4){0.f, 0.f, 0.f, 0.f};
    #pragma unroll 2
    for (int l = 0; l < NL; l += 2) {
        f32x4 f0 = *(const f32x4*)(fp + (size_t)l * ENC);
        f32x4 f1 = *(const f32x4*)(fp + (size_t)(l + 1) * ENC);
        acc0 += al[l] * f0;
        acc1 += al[l + 1] * f1;
    }
    f32x4 rsum = acc0 + acc1;
    *(f32x4*)(ctx + (size_t)b * ENC + e0) = rsum;
}

extern "C" void kernel_launch(void* const* d_in, const int* in_sizes, int n_in,
                              void* d_out, int out_size, void* d_ws, size_t ws_size,
                              hipStream_t stream) {
    const float* feat   = (const float*)d_in[0];
    const float* hidden = (const float*)d_in[1];
    const float* Uw     = (const float*)d_in[2];
    const float* Ub     = (const float*)d_in[3];
    const float* Ww     = (const float*)d_in[4];
    const float* Wb     = (const float*)d_in[5];
    const float* Aw     = (const float*)d_in[6];
    const float* Ab     = (const float*)d_in[7];

    float* out   = (float*)d_out;
    float* alpha = out;              // [128*196]
    float* ctx   = out + MTOT;       // [128*2048]

    char* ws = (char*)d_ws;
    float*          wahb = (float*)ws;                                   // 256 KB
    unsigned short* uwT  = (unsigned short*)(ws + 262144);               // 2 MB
    float*          partb= (float*)(ws + 262144 + 2097152);              // 8*25088*4 = 784 KB

    wah_kernel<<<dim3(128), dim3(512), 0, stream>>>(hidden, Ww, Wb, wahb);
    transpose_uw<<<dim3(64, 16), dim3(32, 8), 0, stream>>>(Uw, uwT);
    gemm_score_kernel<<<dim3(784), dim3(256), 0, stream>>>(feat, uwT, Ub, wahb, Aw, partb);
    softmax_kernel<<<dim3(128), dim3(256), 0, stream>>>(partb, Ab, alpha);
    context_kernel<<<dim3(128, 4), dim3(128), 0, stream>>>(feat, alpha, ctx);
}